// Round 3
// baseline (5142.586 us; speedup 1.0000x reference)
//
#include <hip/hip_runtime.h>

// ---------------------------------------------------------------------------
// BiMambaEncoderBlock on MI355X (gfx950). fp32 accumulate throughout.
// B=2, S=1024, D_MODEL=256, D_INNER=512, D_STATE=64, DT_RANK=16, D_CONV=4.
// Round 3: dtype-adaptive. A detect kernel decides whether d_in is float32 or
// bf16; all true-input loads and the d_out store switch on that device flag.
// Intermediates are stored in our own bf16 workspace format either way.
// ---------------------------------------------------------------------------

typedef unsigned short u16;

static constexpr int ROWS = 2048;   // B*S
static constexpr int DM   = 256;    // d_model
static constexpr int DI   = 512;    // d_inner
static constexpr int NXZ  = 1024;   // 2*d_inner
static constexpr int NDBL = 144;    // dt_rank + 2*d_state
static constexpr int DS   = 64;     // d_state

__device__ __forceinline__ float bf2f(u16 u) {
  union { unsigned u32; float f; } v; v.u32 = ((unsigned)u) << 16; return v.f;
}
__device__ __forceinline__ u16 f2bf(float f) {
  union { float f; unsigned u; } v; v.f = f;
  unsigned r = v.u + 0x7FFFu + ((v.u >> 16) & 1u);   // RNE (finite inputs)
  return (u16)(r >> 16);
}
// load element i of a true kernel input, dtype chosen by flag
__device__ __forceinline__ float ldx(const void* p, size_t i, int f32) {
  return f32 ? ((const float*)p)[i] : bf2f(((const u16*)p)[i]);
}

// ---- workspace layout (bytes) ----
static constexpr size_t XN_OFF   = 0;                                     // bf16 [2048][256]
static constexpr size_t XZ_OFF   = XN_OFF   + (size_t)ROWS * DM * 2;      // bf16 [2][2048][1024]
static constexpr size_t XC_OFF   = XZ_OFF   + (size_t)2 * ROWS * NXZ * 2; // bf16 [2][2048][512]
static constexpr size_t DBL_OFF  = XC_OFF   + (size_t)2 * ROWS * DI * 2;  // bf16 [4096][144]
static constexpr size_t DT_OFF   = DBL_OFF  + (size_t)2 * ROWS * NDBL * 2;// bf16 [2][2048][512]
static constexpr size_t Y_OFF    = DT_OFF   + (size_t)2 * ROWS * DI * 2;  // bf16 [2][2048][512]
static constexpr size_t XSSM_OFF = Y_OFF    + (size_t)2 * ROWS * DI * 2;  // f32  [2048][256]
static constexpr size_t X2_OFF   = XSSM_OFF + (size_t)ROWS * DM * 4;      // bf16 [2048][256]
static constexpr size_t FLAG_OFF = X2_OFF   + (size_t)ROWS * DM * 2;      // int
// total ≈ 25.3 MiB

// ---------------------------------------------------------------------------
// K0: dtype detect. If x is bf16, every u16 is a bf16 of ~N(0,1): |v| small.
// If x is float32, even u16s are raw low mantissa bits -> uniform random bf16
// patterns; P(256 samples all inside ±1024) ~ 1e-70. NaN/inf also trigger.
// ---------------------------------------------------------------------------
__global__ void detect_kernel(const void* __restrict__ x, int* __restrict__ flag) {
  if (threadIdx.x == 0 && blockIdx.x == 0) {
    const u16* p = (const u16*)x;
    int f32 = 0;
    for (int i = 0; i < 512; i += 2) {
      float v = bf2f(p[i]);
      if (!(v > -1024.0f && v < 1024.0f)) f32 = 1;   // catches NaN too
    }
    *flag = f32;
  }
}

// ---------------------------------------------------------------------------
// K1: LayerNorm over d_model=256 (input x -> bf16 ws). 1 block (256 thr)/row.
// ---------------------------------------------------------------------------
__global__ __launch_bounds__(256) void ln1_kernel(
    const void* __restrict__ x, const void* __restrict__ g,
    const void* __restrict__ b, u16* __restrict__ out,
    const int* __restrict__ flagp) {
  int f32 = *flagp;
  int row = blockIdx.x, tid = threadIdx.x;
  float v = ldx(x, (size_t)row * DM + tid, f32);
  float s = v, s2 = v * v;
  for (int o = 32; o; o >>= 1) { s += __shfl_xor(s, o); s2 += __shfl_xor(s2, o); }
  __shared__ float ls[4], ls2[4];
  int wid = tid >> 6;
  if ((tid & 63) == 0) { ls[wid] = s; ls2[wid] = s2; }
  __syncthreads();
  s  = ls[0] + ls[1] + ls[2] + ls[3];
  s2 = ls2[0] + ls2[1] + ls2[2] + ls2[3];
  float mu  = s * (1.0f / DM);
  float var = s2 * (1.0f / DM) - mu * mu;
  float r   = rsqrtf(var + 1e-5f);
  float xn  = (v - mu) * r * ldx(g, tid, f32) + ldx(b, tid, f32);
  out[(size_t)row * DM + tid] = f2bf(xn);
}

// same but f32 ws input (x_ssm)
__global__ __launch_bounds__(256) void ln2_kernel(
    const float* __restrict__ x, const void* __restrict__ g,
    const void* __restrict__ b, u16* __restrict__ out,
    const int* __restrict__ flagp) {
  int f32 = *flagp;
  int row = blockIdx.x, tid = threadIdx.x;
  float v = x[(size_t)row * DM + tid];
  float s = v, s2 = v * v;
  for (int o = 32; o; o >>= 1) { s += __shfl_xor(s, o); s2 += __shfl_xor(s2, o); }
  __shared__ float ls[4], ls2[4];
  int wid = tid >> 6;
  if ((tid & 63) == 0) { ls[wid] = s; ls2[wid] = s2; }
  __syncthreads();
  s  = ls[0] + ls[1] + ls[2] + ls[3];
  s2 = ls2[0] + ls2[1] + ls2[2] + ls2[3];
  float mu  = s * (1.0f / DM);
  float var = s2 * (1.0f / DM) - mu * mu;
  float r   = rsqrtf(var + 1e-5f);
  float xn  = (v - mu) * r * ldx(g, tid, f32) + ldx(b, tid, f32);
  out[(size_t)row * DM + tid] = f2bf(xn);
}

// ---------------------------------------------------------------------------
// K2: in-projection. xz[dir][m][n] = dot(xn[srow], W[n])  (K=256).
// dir=1 reads time-flipped rows. grid (4, 2048, 2), block 256.
// ---------------------------------------------------------------------------
__global__ __launch_bounds__(256) void inproj_kernel(
    const u16* __restrict__ xn, const void* __restrict__ f_w,
    const void* __restrict__ b_w, u16* __restrict__ xz,
    const int* __restrict__ flagp) {
  int f32 = *flagp;
  int tid = threadIdx.x;
  int n   = blockIdx.x * 256 + tid;
  int m   = blockIdx.y;
  int dir = blockIdx.z;
  int bb = m >> 10, t = m & 1023;
  int srow = dir ? (bb * 1024 + (1023 - t)) : m;
  __shared__ float a[DM];
  a[tid] = bf2f(xn[(size_t)srow * DM + tid]);
  __syncthreads();
  const void* W = dir ? b_w : f_w;
  float acc = 0.0f;
#pragma unroll 8
  for (int k = 0; k < DM; ++k) acc += a[k] * ldx(W, (size_t)n * DM + k, f32);
  xz[((size_t)dir * ROWS + m) * NXZ + n] = f2bf(acc);
}

// ---------------------------------------------------------------------------
// K3: depthwise causal conv (width 4) + silu. 1 thread per (dir,row,d).
// ---------------------------------------------------------------------------
__global__ __launch_bounds__(256) void conv_kernel(
    const u16* __restrict__ xz, const void* __restrict__ f_cw,
    const void* __restrict__ f_cb, const void* __restrict__ b_cw,
    const void* __restrict__ b_cb, u16* __restrict__ xc,
    const int* __restrict__ flagp) {
  int f32 = *flagp;
  int idx = blockIdx.x * 256 + threadIdx.x;   // [0, 2*2048*512)
  int d   = idx & (DI - 1);
  int row = (idx >> 9) & (ROWS - 1);
  int dir = idx >> 20;
  int tpos = row & 1023;
  const void* cw = dir ? b_cw : f_cw;
  const void* cb = dir ? b_cb : f_cb;
  const u16* xi = xz + (size_t)dir * ROWS * NXZ;
  float s = ldx(cb, d, f32);
#pragma unroll
  for (int k = 0; k < 4; ++k) {
    int tt = tpos - 3 + k;
    if (tt >= 0)
      s += ldx(cw, d * 4 + k, f32) * bf2f(xi[(size_t)(row + k - 3) * NXZ + d]);
  }
  float sl = s / (1.0f + __expf(-s));
  xc[idx] = f2bf(sl);
}

// ---------------------------------------------------------------------------
// K4: x-projection. dbl[m][n] = dot(xc[m], W[n])  (K=512), m in [0,4096).
// ---------------------------------------------------------------------------
__global__ __launch_bounds__(256) void xproj_kernel(
    const u16* __restrict__ xc, const void* __restrict__ f_w,
    const void* __restrict__ b_w, u16* __restrict__ dbl,
    const int* __restrict__ flagp) {
  int f32 = *flagp;
  int flat = blockIdx.x * 256 + threadIdx.x;  // [0, 4096*144)
  int m = flat / NDBL;
  int n = flat - m * NDBL;
  const void* W  = (m & 2048) ? b_w : f_w;
  const u16* ar = xc + (size_t)m * DI;
  float acc = 0.0f;
#pragma unroll 8
  for (int k = 0; k < DI; ++k) acc += bf2f(ar[k]) * ldx(W, (size_t)n * DI + k, f32);
  dbl[(size_t)m * NDBL + n] = f2bf(acc);
}

// ---------------------------------------------------------------------------
// K5: dt = softplus(dbl[:, :16] @ dt_w.T + dt_b). 1 thread per (m,n). K=16.
// ---------------------------------------------------------------------------
__global__ __launch_bounds__(256) void dtproj_kernel(
    const u16* __restrict__ dbl, const void* __restrict__ f_dw,
    const void* __restrict__ f_db, const void* __restrict__ b_dw,
    const void* __restrict__ b_db, u16* __restrict__ dt,
    const int* __restrict__ flagp) {
  int f32 = *flagp;
  int idx = blockIdx.x * 256 + threadIdx.x;   // [0, 4096*512)
  int n = idx & (DI - 1);
  int m = idx >> 9;                            // [0, 4096)
  int dir = m >> 11;
  const void* dw = dir ? b_dw : f_dw;
  const void* db = dir ? b_db : f_db;
  float acc = ldx(db, n, f32);
  const u16* drow = dbl + (size_t)m * NDBL;
#pragma unroll
  for (int k = 0; k < 16; ++k)
    acc += bf2f(drow[k]) * ldx(dw, n * 16 + k, f32);
  float sp = (acc > 20.0f) ? acc : log1pf(__expf(acc));
  dt[idx] = f2bf(sp);
}

// ---------------------------------------------------------------------------
// K6: selective scan. One wave per (dir, b, d); lane = state index.
// h = exp(dt*A)*h + dt*B*xc;  y = sum_n(h*C);  y = (y + xc*Dp)*silu(z).
// ---------------------------------------------------------------------------
__global__ __launch_bounds__(256) void scan_kernel(
    const u16* __restrict__ dt, const u16* __restrict__ xc,
    const u16* __restrict__ xz, const u16* __restrict__ dbl,
    const void* __restrict__ f_Al, const void* __restrict__ f_Dp,
    const void* __restrict__ b_Al, const void* __restrict__ b_Dp,
    u16* __restrict__ y, const int* __restrict__ flagp) {
  int f32 = *flagp;
  int gw   = blockIdx.x * 4 + (threadIdx.x >> 6);  // [0, 2048)
  int lane = threadIdx.x & 63;
  int d   = gw & (DI - 1);
  int bb  = (gw >> 9) & 1;
  int dir = gw >> 10;
  const void* Al = dir ? b_Al : f_Al;
  float A   = -__expf(ldx(Al, d * DS + lane, f32));
  float Dpd = ldx(dir ? b_Dp : f_Dp, d, f32);
  size_t rowbase = ((size_t)dir * ROWS + bb * 1024) * DI;
  size_t dblbase = ((size_t)dir * ROWS + bb * 1024) * NDBL;
  size_t zbase   = ((size_t)dir * ROWS + bb * 1024) * NXZ;
  float h = 0.0f;
  for (int t = 0; t < 1024; ++t) {
    float dtv = bf2f(dt[rowbase + (size_t)t * DI + d]);
    float xcv = bf2f(xc[rowbase + (size_t)t * DI + d]);
    float Bv  = bf2f(dbl[dblbase + (size_t)t * NDBL + 16 + lane]);
    float Cv  = bf2f(dbl[dblbase + (size_t)t * NDBL + 80 + lane]);
    h = __expf(dtv * A) * h + dtv * Bv * xcv;
    float p = h * Cv;
    for (int o = 32; o; o >>= 1) p += __shfl_xor(p, o);
    if (lane == 0) {
      float zv = bf2f(xz[zbase + (size_t)t * NXZ + DI + d]);
      float yv = (p + xcv * Dpd) * (zv / (1.0f + __expf(-zv)));
      y[rowbase + (size_t)t * DI + d] = f2bf(yv);
    }
  }
}

// ---------------------------------------------------------------------------
// K7: out-projection + combine dirs (K=512 each dir). 1 block per row.
// ---------------------------------------------------------------------------
__global__ __launch_bounds__(256) void outproj_kernel(
    const u16* __restrict__ y, const void* __restrict__ f_ow,
    const void* __restrict__ b_ow, float* __restrict__ xssm,
    const int* __restrict__ flagp) {
  int f32 = *flagp;
  int m = blockIdx.x, n = threadIdx.x;
  int bb = m >> 10, t = m & 1023;
  int rowb = ROWS + bb * 1024 + (1023 - t);
  __shared__ float yf[DI], yb[DI];
  for (int i = threadIdx.x; i < DI; i += 256) {
    yf[i] = bf2f(y[(size_t)m * DI + i]);
    yb[i] = bf2f(y[(size_t)rowb * DI + i]);
  }
  __syncthreads();
  float acc = 0.0f;
#pragma unroll 8
  for (int k = 0; k < DI; ++k) acc += yf[k] * ldx(f_ow, (size_t)n * DI + k, f32);
#pragma unroll 8
  for (int k = 0; k < DI; ++k) acc += yb[k] * ldx(b_ow, (size_t)n * DI + k, f32);
  xssm[(size_t)m * DM + n] = acc;
}

// ---------------------------------------------------------------------------
// K9: out = gelu_exact(x2 @ w2.T + b2). Output dtype follows the flag.
// ---------------------------------------------------------------------------
__global__ __launch_bounds__(256) void final_kernel(
    const u16* __restrict__ x2, const void* __restrict__ w2,
    const void* __restrict__ b2, void* __restrict__ out,
    const int* __restrict__ flagp) {
  int f32 = *flagp;
  int m = blockIdx.x, n = threadIdx.x;
  __shared__ float a[DM];
  a[n] = bf2f(x2[(size_t)m * DM + n]);
  __syncthreads();
  float acc = 0.0f;
#pragma unroll 8
  for (int k = 0; k < DM; ++k) acc += a[k] * ldx(w2, (size_t)n * DM + k, f32);
  float v = acc + ldx(b2, n, f32);
  float gl = 0.5f * v * (1.0f + erff(v * 0.70710678118654752f));
  size_t o = (size_t)m * DM + n;
  if (f32) ((float*)out)[o] = gl;
  else     ((u16*)out)[o]   = f2bf(gl);
}

// ---------------------------------------------------------------------------
extern "C" void kernel_launch(void* const* d_in, const int* in_sizes, int n_in,
                              void* d_out, int out_size, void* d_ws, size_t ws_size,
                              hipStream_t stream) {
  const void* x        = d_in[0];
  const void* f_in_w   = d_in[1];
  const void* f_conv_w = d_in[2];
  const void* f_conv_b = d_in[3];
  const void* f_xproj  = d_in[4];
  const void* f_dt_w   = d_in[5];
  const void* f_dt_b   = d_in[6];
  const void* f_A_log  = d_in[7];
  const void* f_Dp     = d_in[8];
  const void* f_out_w  = d_in[9];
  const void* b_in_w   = d_in[10];
  const void* b_conv_w = d_in[11];
  const void* b_conv_b = d_in[12];
  const void* b_xproj  = d_in[13];
  const void* b_dt_w   = d_in[14];
  const void* b_dt_b   = d_in[15];
  const void* b_A_log  = d_in[16];
  const void* b_Dp     = d_in[17];
  const void* b_out_w  = d_in[18];
  const void* ln1_g    = d_in[19];
  const void* ln1_b    = d_in[20];
  const void* ln2_g    = d_in[21];
  const void* ln2_b    = d_in[22];
  const void* w2       = d_in[23];
  const void* b2       = d_in[24];

  char* ws = (char*)d_ws;
  u16*   xn   = (u16*)(ws + XN_OFF);
  u16*   xz   = (u16*)(ws + XZ_OFF);
  u16*   xc   = (u16*)(ws + XC_OFF);
  u16*   dbl  = (u16*)(ws + DBL_OFF);
  u16*   dt   = (u16*)(ws + DT_OFF);
  u16*   y    = (u16*)(ws + Y_OFF);
  float* xssm = (float*)(ws + XSSM_OFF);
  u16*   x2   = (u16*)(ws + X2_OFF);
  int*   flag = (int*)(ws + FLAG_OFF);

  detect_kernel<<<1, 64, 0, stream>>>(x, flag);
  ln1_kernel<<<ROWS, 256, 0, stream>>>(x, ln1_g, ln1_b, xn, flag);
  inproj_kernel<<<dim3(4, ROWS, 2), 256, 0, stream>>>(xn, f_in_w, b_in_w, xz, flag);
  conv_kernel<<<(2 * ROWS * DI) / 256, 256, 0, stream>>>(
      xz, f_conv_w, f_conv_b, b_conv_w, b_conv_b, xc, flag);
  xproj_kernel<<<(2 * ROWS * NDBL) / 256, 256, 0, stream>>>(xc, f_xproj, b_xproj, dbl, flag);
  dtproj_kernel<<<(2 * ROWS * DI) / 256, 256, 0, stream>>>(
      dbl, f_dt_w, f_dt_b, b_dt_w, b_dt_b, dt, flag);
  scan_kernel<<<512, 256, 0, stream>>>(dt, xc, xz, dbl, f_A_log, f_Dp, b_A_log, b_Dp, y, flag);
  outproj_kernel<<<ROWS, 256, 0, stream>>>(y, f_out_w, b_out_w, xssm, flag);
  ln2_kernel<<<ROWS, 256, 0, stream>>>(xssm, ln2_g, ln2_b, x2, flag);
  final_kernel<<<ROWS, 256, 0, stream>>>(x2, w2, b2, d_out, flag);
}

// Round 4
// 1043.101 us; speedup vs baseline: 4.9301x; 4.9301x over previous
//
#include <hip/hip_runtime.h>

// ---------------------------------------------------------------------------
// BiMambaEncoderBlock on MI355X (gfx950). fp32 accumulate, bf16 intermediates.
// B=2, S=1024, D_MODEL=256, D_INNER=512, D_STATE=64, DT_RANK=16, D_CONV=4.
// Round 4: dtype-adaptive input load (flag in ws) + bf16 weight conversion +
// MFMA (16x16x32 bf16) for all four projections. Scan/conv/LN as round 3.
// ---------------------------------------------------------------------------

typedef unsigned short u16;
typedef short bf16x8 __attribute__((ext_vector_type(8)));   // 8 bf16 = 4 VGPRs
typedef float f32x4  __attribute__((ext_vector_type(4)));

#define MFMA(a, b, c) __builtin_amdgcn_mfma_f32_16x16x32_bf16((a), (b), (c), 0, 0, 0)

static constexpr int ROWS = 2048;   // B*S
static constexpr int DM   = 256;    // d_model
static constexpr int DI   = 512;    // d_inner
static constexpr int NXZ  = 1024;   // 2*d_inner
static constexpr int NDBL = 144;    // dt_rank + 2*d_state
static constexpr int DS   = 64;     // d_state

__device__ __forceinline__ float bf2f(u16 u) {
  union { unsigned u32; float f; } v; v.u32 = ((unsigned)u) << 16; return v.f;
}
__device__ __forceinline__ u16 f2bf(float f) {
  union { float f; unsigned u; } v; v.f = f;
  unsigned r = v.u + 0x7FFFu + ((v.u >> 16) & 1u);   // RNE (finite inputs)
  return (u16)(r >> 16);
}
__device__ __forceinline__ float ldx(const void* p, size_t i, int f32) {
  return f32 ? ((const float*)p)[i] : bf2f(((const u16*)p)[i]);
}

// ---- workspace layout (bytes) ----
static constexpr size_t XN_OFF   = 0;                                     // bf16 [2048][256]
static constexpr size_t XZ_OFF   = XN_OFF   + (size_t)ROWS * DM * 2;      // bf16 [2][2048][1024]
static constexpr size_t XC_OFF   = XZ_OFF   + (size_t)2 * ROWS * NXZ * 2; // bf16 [2][2048][512]
static constexpr size_t DBL_OFF  = XC_OFF   + (size_t)2 * ROWS * DI * 2;  // bf16 [4096][144]
static constexpr size_t DT_OFF   = DBL_OFF  + (size_t)2 * ROWS * NDBL * 2;// bf16 [2][2048][512]
static constexpr size_t Y_OFF    = DT_OFF   + (size_t)2 * ROWS * DI * 2;  // bf16 [2][2048][512]
static constexpr size_t XSSM_OFF = Y_OFF    + (size_t)2 * ROWS * DI * 2;  // f32  [2048][256]
static constexpr size_t X2_OFF   = XSSM_OFF + (size_t)ROWS * DM * 4;      // bf16 [2048][256]
static constexpr size_t FLAG_OFF = X2_OFF   + (size_t)ROWS * DM * 2;      // int
static constexpr size_t WB_OFF   = FLAG_OFF + 16;                         // bf16 weights
// converted-weight region (element offsets within WB):
static constexpr int WB_IWF = 0;        // f_in_w  [1024][256]
static constexpr int WB_IWB = 262144;   // b_in_w  [1024][256]
static constexpr int WB_XPF = 524288;   // f_xproj [144][512]
static constexpr int WB_XPB = 598016;   // b_xproj [144][512]
static constexpr int WB_OWF = 671744;   // f_out_w [256][512]
static constexpr int WB_OWB = 802816;   // b_out_w [256][512]
static constexpr int WB_W2  = 933888;   // w2      [256][256]
static constexpr int WB_DWF = 999424;   // f_dt_w  [512][16]
static constexpr int WB_DWB = 1007616;  // b_dt_w  [512][16]
static constexpr int WB_TOT = 1015808;
// total ws ≈ 27.3 MiB

// ---------------------------------------------------------------------------
// K0: dtype detect (f32 vs bf16), see round 3.
// ---------------------------------------------------------------------------
__global__ void detect_kernel(const void* __restrict__ x, int* __restrict__ flag) {
  if (threadIdx.x == 0 && blockIdx.x == 0) {
    const u16* p = (const u16*)x;
    int f32 = 0;
    for (int i = 0; i < 512; i += 2) {
      float v = bf2f(p[i]);
      if (!(v > -1024.0f && v < 1024.0f)) f32 = 1;
    }
    *flag = f32;
  }
}

// ---------------------------------------------------------------------------
// K0b: convert all GEMM weights to bf16 into ws (identity if already bf16).
// ---------------------------------------------------------------------------
__global__ __launch_bounds__(256) void convert_kernel(
    const void* __restrict__ f_iw, const void* __restrict__ b_iw,
    const void* __restrict__ f_xp, const void* __restrict__ b_xp,
    const void* __restrict__ f_ow, const void* __restrict__ b_ow,
    const void* __restrict__ w2,   const void* __restrict__ f_dw,
    const void* __restrict__ b_dw, u16* __restrict__ wb,
    const int* __restrict__ flagp) {
  int f32 = *flagp;
  int i = blockIdx.x * 256 + threadIdx.x;
  if (i >= WB_TOT) return;
  const void* src; int off;
  if      (i < WB_IWB) { src = f_iw; off = i - WB_IWF; }
  else if (i < WB_XPF) { src = b_iw; off = i - WB_IWB; }
  else if (i < WB_XPB) { src = f_xp; off = i - WB_XPF; }
  else if (i < WB_OWF) { src = b_xp; off = i - WB_XPB; }
  else if (i < WB_OWB) { src = f_ow; off = i - WB_OWF; }
  else if (i < WB_W2)  { src = b_ow; off = i - WB_OWB; }
  else if (i < WB_DWF) { src = w2;   off = i - WB_W2;  }
  else if (i < WB_DWB) { src = f_dw; off = i - WB_DWF; }
  else                 { src = b_dw; off = i - WB_DWB; }
  wb[i] = f2bf(ldx(src, (size_t)off, f32));
}

// ---------------------------------------------------------------------------
// K1: LayerNorm over d_model=256 (input x -> bf16 ws). 1 block/row.
// ---------------------------------------------------------------------------
__global__ __launch_bounds__(256) void ln1_kernel(
    const void* __restrict__ x, const void* __restrict__ g,
    const void* __restrict__ b, u16* __restrict__ out,
    const int* __restrict__ flagp) {
  int f32 = *flagp;
  int row = blockIdx.x, tid = threadIdx.x;
  float v = ldx(x, (size_t)row * DM + tid, f32);
  float s = v, s2 = v * v;
  for (int o = 32; o; o >>= 1) { s += __shfl_xor(s, o); s2 += __shfl_xor(s2, o); }
  __shared__ float ls[4], ls2[4];
  int wid = tid >> 6;
  if ((tid & 63) == 0) { ls[wid] = s; ls2[wid] = s2; }
  __syncthreads();
  s  = ls[0] + ls[1] + ls[2] + ls[3];
  s2 = ls2[0] + ls2[1] + ls2[2] + ls2[3];
  float mu  = s * (1.0f / DM);
  float var = s2 * (1.0f / DM) - mu * mu;
  float r   = rsqrtf(var + 1e-5f);
  float xn  = (v - mu) * r * ldx(g, tid, f32) + ldx(b, tid, f32);
  out[(size_t)row * DM + tid] = f2bf(xn);
}

// same but f32 ws input (x_ssm)
__global__ __launch_bounds__(256) void ln2_kernel(
    const float* __restrict__ x, const void* __restrict__ g,
    const void* __restrict__ b, u16* __restrict__ out,
    const int* __restrict__ flagp) {
  int f32 = *flagp;
  int row = blockIdx.x, tid = threadIdx.x;
  float v = x[(size_t)row * DM + tid];
  float s = v, s2 = v * v;
  for (int o = 32; o; o >>= 1) { s += __shfl_xor(s, o); s2 += __shfl_xor(s2, o); }
  __shared__ float ls[4], ls2[4];
  int wid = tid >> 6;
  if ((tid & 63) == 0) { ls[wid] = s; ls2[wid] = s2; }
  __syncthreads();
  s  = ls[0] + ls[1] + ls[2] + ls[3];
  s2 = ls2[0] + ls2[1] + ls2[2] + ls2[3];
  float mu  = s * (1.0f / DM);
  float var = s2 * (1.0f / DM) - mu * mu;
  float r   = rsqrtf(var + 1e-5f);
  float xn  = (v - mu) * r * ldx(g, tid, f32) + ldx(b, tid, f32);
  out[(size_t)row * DM + tid] = f2bf(xn);
}

// ---------------------------------------------------------------------------
// K2: in-projection (MFMA). xz[dir][m][:] = xn[srow(m)] @ in_w.T  (K=256).
// grid (128, 4, 2), block 256. Wave: 16m x 64n.
// ---------------------------------------------------------------------------
__global__ __launch_bounds__(256) void inproj_kernel(
    const u16* __restrict__ xn, const u16* __restrict__ wb,
    u16* __restrict__ xz) {
  int dir  = blockIdx.z;
  int wave = threadIdx.x >> 6, lane = threadIdx.x & 63;
  int m0 = blockIdx.x * 16;
  int n0 = blockIdx.y * 256 + wave * 64;
  int lm = lane & 15, quad = lane >> 4;
  const short* W = (const short*)(wb + (dir ? WB_IWB : WB_IWF));
  const short* X = (const short*)xn;
  int m = m0 + lm;
  int bb = m >> 10, t = m & 1023;
  int srow = dir ? (bb * 1024 + (1023 - t)) : m;
  f32x4 acc[4] = {};
  for (int k0 = 0; k0 < DM; k0 += 32) {
    bf16x8 a = *(const bf16x8*)(X + (size_t)srow * DM + k0 + quad * 8);
#pragma unroll
    for (int c = 0; c < 4; ++c) {
      bf16x8 bf = *(const bf16x8*)(W + (size_t)(n0 + c * 16 + lm) * DM + k0 + quad * 8);
      acc[c] = MFMA(a, bf, acc[c]);
    }
  }
  u16* out = xz + (size_t)dir * ROWS * NXZ;
#pragma unroll
  for (int c = 0; c < 4; ++c)
#pragma unroll
    for (int r = 0; r < 4; ++r)
      out[(size_t)(m0 + quad * 4 + r) * NXZ + n0 + c * 16 + lm] = f2bf(acc[c][r]);
}

// ---------------------------------------------------------------------------
// K3: depthwise causal conv (width 4) + silu. 1 thread per (dir,row,d).
// ---------------------------------------------------------------------------
__global__ __launch_bounds__(256) void conv_kernel(
    const u16* __restrict__ xz, const void* __restrict__ f_cw,
    const void* __restrict__ f_cb, const void* __restrict__ b_cw,
    const void* __restrict__ b_cb, u16* __restrict__ xc,
    const int* __restrict__ flagp) {
  int f32 = *flagp;
  int idx = blockIdx.x * 256 + threadIdx.x;   // [0, 2*2048*512)
  int d   = idx & (DI - 1);
  int row = (idx >> 9) & (ROWS - 1);
  int dir = idx >> 20;
  int tpos = row & 1023;
  const void* cw = dir ? b_cw : f_cw;
  const void* cb = dir ? b_cb : f_cb;
  const u16* xi = xz + (size_t)dir * ROWS * NXZ;
  float s = ldx(cb, d, f32);
#pragma unroll
  for (int k = 0; k < 4; ++k) {
    int tt = tpos - 3 + k;
    if (tt >= 0)
      s += ldx(cw, d * 4 + k, f32) * bf2f(xi[(size_t)(row + k - 3) * NXZ + d]);
  }
  float sl = s / (1.0f + __expf(-s));
  xc[idx] = f2bf(sl);
}

// ---------------------------------------------------------------------------
// K4: x-projection (MFMA). dbl[m][n] = xc[m] @ xproj_w.T  (K=512).
// grid (64, 9), block 256 (4 waves along m). Wave: 16m x 16n.
// ---------------------------------------------------------------------------
__global__ __launch_bounds__(256) void xproj_kernel(
    const u16* __restrict__ xc, const u16* __restrict__ wb,
    u16* __restrict__ dbl) {
  int wave = threadIdx.x >> 6, lane = threadIdx.x & 63;
  int m0 = blockIdx.x * 64 + wave * 16;          // [0, 4096)
  int n0 = blockIdx.y * 16;
  int lm = lane & 15, quad = lane >> 4;
  const short* W = (const short*)(wb + ((m0 & 2048) ? WB_XPB : WB_XPF));
  const short* X = (const short*)xc;
  f32x4 acc = {};
  for (int k0 = 0; k0 < DI; k0 += 32) {
    bf16x8 a  = *(const bf16x8*)(X + (size_t)(m0 + lm) * DI + k0 + quad * 8);
    bf16x8 bf = *(const bf16x8*)(W + (size_t)(n0 + lm) * DI + k0 + quad * 8);
    acc = MFMA(a, bf, acc);
  }
#pragma unroll
  for (int r = 0; r < 4; ++r)
    dbl[(size_t)(m0 + quad * 4 + r) * NDBL + n0 + lm] = f2bf(acc[r]);
}

// ---------------------------------------------------------------------------
// K5: dt = softplus(dbl[:, :16] @ dt_w.T + dt_b). LDS-staged weights.
// grid 8192 (block = (m, half)), block 256.
// ---------------------------------------------------------------------------
__global__ __launch_bounds__(256) void dtproj_kernel(
    const u16* __restrict__ dbl, const u16* __restrict__ wb,
    const void* __restrict__ f_db, const void* __restrict__ b_db,
    u16* __restrict__ dt, const int* __restrict__ flagp) {
  int f32 = *flagp;
  int blk  = blockIdx.x;
  int m    = blk >> 1, half = blk & 1;
  int tid  = threadIdx.x;
  int n    = half * 256 + tid;
  int dir  = m >> 11;
  const u16* dw = wb + (dir ? WB_DWB : WB_DWF) + half * 256 * 16;
  __shared__ float dws[256 * 17];   // stride 17: conflict-free
  __shared__ float drow[16];
  for (int i = tid; i < 4096; i += 256)
    dws[(i >> 4) * 17 + (i & 15)] = bf2f(dw[i]);
  if (tid < 16) drow[tid] = bf2f(dbl[(size_t)m * NDBL + tid]);
  __syncthreads();
  float acc = ldx(dir ? b_db : f_db, n, f32);
#pragma unroll
  for (int k = 0; k < 16; ++k) acc += drow[k] * dws[tid * 17 + k];
  float sp = (acc > 20.0f) ? acc : log1pf(__expf(acc));
  dt[(size_t)m * DI + n] = f2bf(sp);
}

// ---------------------------------------------------------------------------
// K6: selective scan. One wave per (dir, b, d); lane = state index.
// ---------------------------------------------------------------------------
__global__ __launch_bounds__(256) void scan_kernel(
    const u16* __restrict__ dt, const u16* __restrict__ xc,
    const u16* __restrict__ xz, const u16* __restrict__ dbl,
    const void* __restrict__ f_Al, const void* __restrict__ f_Dp,
    const void* __restrict__ b_Al, const void* __restrict__ b_Dp,
    u16* __restrict__ y, const int* __restrict__ flagp) {
  int f32 = *flagp;
  int gw   = blockIdx.x * 4 + (threadIdx.x >> 6);  // [0, 2048)
  int lane = threadIdx.x & 63;
  int d   = gw & (DI - 1);
  int bb  = (gw >> 9) & 1;
  int dir = gw >> 10;
  const void* Al = dir ? b_Al : f_Al;
  float A   = -__expf(ldx(Al, d * DS + lane, f32));
  float Dpd = ldx(dir ? b_Dp : f_Dp, d, f32);
  size_t rowbase = ((size_t)dir * ROWS + bb * 1024) * DI;
  size_t dblbase = ((size_t)dir * ROWS + bb * 1024) * NDBL;
  size_t zbase   = ((size_t)dir * ROWS + bb * 1024) * NXZ;
  float h = 0.0f;
  for (int t = 0; t < 1024; ++t) {
    float dtv = bf2f(dt[rowbase + (size_t)t * DI + d]);
    float xcv = bf2f(xc[rowbase + (size_t)t * DI + d]);
    float Bv  = bf2f(dbl[dblbase + (size_t)t * NDBL + 16 + lane]);
    float Cv  = bf2f(dbl[dblbase + (size_t)t * NDBL + 80 + lane]);
    h = __expf(dtv * A) * h + dtv * Bv * xcv;
    float p = h * Cv;
    for (int o = 32; o; o >>= 1) p += __shfl_xor(p, o);
    if (lane == 0) {
      float zv = bf2f(xz[zbase + (size_t)t * NXZ + DI + d]);
      float yv = (p + xcv * Dpd) * (zv / (1.0f + __expf(-zv)));
      y[rowbase + (size_t)t * DI + d] = f2bf(yv);
    }
  }
}

// ---------------------------------------------------------------------------
// K7: out-projection (MFMA) + combine dirs. K=512 per dir.
// grid 128, block 256 (4 waves along n). Wave: 16m x 64n.
// ---------------------------------------------------------------------------
__global__ __launch_bounds__(256) void outproj_kernel(
    const u16* __restrict__ y, const u16* __restrict__ wb,
    float* __restrict__ xssm) {
  int wave = threadIdx.x >> 6, lane = threadIdx.x & 63;
  int m0 = blockIdx.x * 16;
  int n0 = wave * 64;
  int lm = lane & 15, quad = lane >> 4;
  const short* Y = (const short*)y;
  int m  = m0 + lm;
  int bb = m >> 10, t = m & 1023;
  int srow_b = ROWS + bb * 1024 + (1023 - t);
  f32x4 acc[4] = {};
  {
    const short* W = (const short*)(wb + WB_OWF);
    for (int k0 = 0; k0 < DI; k0 += 32) {
      bf16x8 a = *(const bf16x8*)(Y + (size_t)m * DI + k0 + quad * 8);
#pragma unroll
      for (int c = 0; c < 4; ++c) {
        bf16x8 bf = *(const bf16x8*)(W + (size_t)(n0 + c * 16 + lm) * DI + k0 + quad * 8);
        acc[c] = MFMA(a, bf, acc[c]);
      }
    }
  }
  {
    const short* W = (const short*)(wb + WB_OWB);
    for (int k0 = 0; k0 < DI; k0 += 32) {
      bf16x8 a = *(const bf16x8*)(Y + (size_t)srow_b * DI + k0 + quad * 8);
#pragma unroll
      for (int c = 0; c < 4; ++c) {
        bf16x8 bf = *(const bf16x8*)(W + (size_t)(n0 + c * 16 + lm) * DI + k0 + quad * 8);
        acc[c] = MFMA(a, bf, acc[c]);
      }
    }
  }
#pragma unroll
  for (int c = 0; c < 4; ++c)
#pragma unroll
    for (int r = 0; r < 4; ++r)
      xssm[(size_t)(m0 + quad * 4 + r) * DM + n0 + c * 16 + lm] = acc[c][r];
}

// ---------------------------------------------------------------------------
// K9: out = gelu_exact(x2 @ w2.T + b2) (MFMA). grid 128, block 256.
// ---------------------------------------------------------------------------
__global__ __launch_bounds__(256) void final_kernel(
    const u16* __restrict__ x2, const u16* __restrict__ wb,
    const void* __restrict__ b2, void* __restrict__ out,
    const int* __restrict__ flagp) {
  int f32 = *flagp;
  int wave = threadIdx.x >> 6, lane = threadIdx.x & 63;
  int m0 = blockIdx.x * 16;
  int n0 = wave * 64;
  int lm = lane & 15, quad = lane >> 4;
  const short* X = (const short*)x2;
  const short* W = (const short*)(wb + WB_W2);
  f32x4 acc[4] = {};
  for (int k0 = 0; k0 < DM; k0 += 32) {
    bf16x8 a = *(const bf16x8*)(X + (size_t)(m0 + lm) * DM + k0 + quad * 8);
#pragma unroll
    for (int c = 0; c < 4; ++c) {
      bf16x8 bf = *(const bf16x8*)(W + (size_t)(n0 + c * 16 + lm) * DM + k0 + quad * 8);
      acc[c] = MFMA(a, bf, acc[c]);
    }
  }
#pragma unroll
  for (int c = 0; c < 4; ++c)
#pragma unroll
    for (int r = 0; r < 4; ++r) {
      int col = n0 + c * 16 + lm;
      float v = acc[c][r] + ldx(b2, col, f32);
      float g = 0.5f * v * (1.0f + erff(v * 0.70710678118654752f));
      size_t o = (size_t)(m0 + quad * 4 + r) * DM + col;
      if (f32) ((float*)out)[o] = g;
      else     ((u16*)out)[o]   = f2bf(g);
    }
}

// ---------------------------------------------------------------------------
extern "C" void kernel_launch(void* const* d_in, const int* in_sizes, int n_in,
                              void* d_out, int out_size, void* d_ws, size_t ws_size,
                              hipStream_t stream) {
  const void* x        = d_in[0];
  const void* f_in_w   = d_in[1];
  const void* f_conv_w = d_in[2];
  const void* f_conv_b = d_in[3];
  const void* f_xproj  = d_in[4];
  const void* f_dt_w   = d_in[5];
  const void* f_dt_b   = d_in[6];
  const void* f_A_log  = d_in[7];
  const void* f_Dp     = d_in[8];
  const void* f_out_w  = d_in[9];
  const void* b_in_w   = d_in[10];
  const void* b_conv_w = d_in[11];
  const void* b_conv_b = d_in[12];
  const void* b_xproj  = d_in[13];
  const void* b_dt_w   = d_in[14];
  const void* b_dt_b   = d_in[15];
  const void* b_A_log  = d_in[16];
  const void* b_Dp     = d_in[17];
  const void* b_out_w  = d_in[18];
  const void* ln1_g    = d_in[19];
  const void* ln1_b    = d_in[20];
  const void* ln2_g    = d_in[21];
  const void* ln2_b    = d_in[22];
  const void* w2       = d_in[23];
  const void* b2       = d_in[24];

  char* ws = (char*)d_ws;
  u16*   xn   = (u16*)(ws + XN_OFF);
  u16*   xz   = (u16*)(ws + XZ_OFF);
  u16*   xc   = (u16*)(ws + XC_OFF);
  u16*   dbl  = (u16*)(ws + DBL_OFF);
  u16*   dt   = (u16*)(ws + DT_OFF);
  u16*   y    = (u16*)(ws + Y_OFF);
  float* xssm = (float*)(ws + XSSM_OFF);
  u16*   x2   = (u16*)(ws + X2_OFF);
  int*   flag = (int*)(ws + FLAG_OFF);
  u16*   wb   = (u16*)(ws + WB_OFF);

  detect_kernel<<<1, 64, 0, stream>>>(x, flag);
  convert_kernel<<<(WB_TOT + 255) / 256, 256, 0, stream>>>(
      f_in_w, b_in_w, f_xproj, b_xproj, f_out_w, b_out_w, w2, f_dt_w, b_dt_w,
      wb, flag);
  ln1_kernel<<<ROWS, 256, 0, stream>>>(x, ln1_g, ln1_b, xn, flag);
  inproj_kernel<<<dim3(ROWS / 16, 4, 2), 256, 0, stream>>>(xn, wb, xz);
  conv_kernel<<<(2 * ROWS * DI) / 256, 256, 0, stream>>>(
      xz, f_conv_w, f_conv_b, b_conv_w, b_conv_b, xc, flag);
  xproj_kernel<<<dim3(64, 9), 256, 0, stream>>>(xc, wb, dbl);
  dtproj_kernel<<<8192, 256, 0, stream>>>(dbl, wb, f_dt_b, b_dt_b, dt, flag);
  scan_kernel<<<512, 256, 0, stream>>>(dt, xc, xz, dbl, f_A_log, f_Dp, b_A_log, b_Dp, y, flag);
  outproj_kernel<<<ROWS / 16, 256, 0, stream>>>(y, wb, xssm);
  ln2_kernel<<<ROWS, 256, 0, stream>>>(xssm, ln2_g, ln2_b, x2, flag);
  final_kernel<<<ROWS / 16, 256, 0, stream>>>(x2, wb, b2, d_out, flag);
}

// Round 5
// 409.154 us; speedup vs baseline: 12.5688x; 2.5494x over previous
//
#include <hip/hip_runtime.h>

// ---------------------------------------------------------------------------
// BiMambaEncoderBlock on MI355X (gfx950). fp32 accumulate, bf16 intermediates.
// B=2, S=1024, D_MODEL=256, D_INNER=512, D_STATE=64, DT_RANK=16, D_CONV=4.
// Round 5: scan unrolled x8 (batched loads, deferred butterflies, lane-j
// stores); dtproj -> per-thread vector loads. MFMA GEMMs as round 4.
// ---------------------------------------------------------------------------

typedef unsigned short u16;
typedef short bf16x8 __attribute__((ext_vector_type(8)));   // 8 bf16 = 4 VGPRs
typedef float f32x4  __attribute__((ext_vector_type(4)));

#define MFMA(a, b, c) __builtin_amdgcn_mfma_f32_16x16x32_bf16((a), (b), (c), 0, 0, 0)

static constexpr int ROWS = 2048;   // B*S
static constexpr int DM   = 256;    // d_model
static constexpr int DI   = 512;    // d_inner
static constexpr int NXZ  = 1024;   // 2*d_inner
static constexpr int NDBL = 144;    // dt_rank + 2*d_state
static constexpr int DS   = 64;     // d_state

__device__ __forceinline__ float bf2f(u16 u) {
  union { unsigned u32; float f; } v; v.u32 = ((unsigned)u) << 16; return v.f;
}
__device__ __forceinline__ u16 f2bf(float f) {
  union { float f; unsigned u; } v; v.f = f;
  unsigned r = v.u + 0x7FFFu + ((v.u >> 16) & 1u);   // RNE (finite inputs)
  return (u16)(r >> 16);
}
__device__ __forceinline__ float ldx(const void* p, size_t i, int f32) {
  return f32 ? ((const float*)p)[i] : bf2f(((const u16*)p)[i]);
}

// ---- workspace layout (bytes) ----
static constexpr size_t XN_OFF   = 0;                                     // bf16 [2048][256]
static constexpr size_t XZ_OFF   = XN_OFF   + (size_t)ROWS * DM * 2;      // bf16 [2][2048][1024]
static constexpr size_t XC_OFF   = XZ_OFF   + (size_t)2 * ROWS * NXZ * 2; // bf16 [2][2048][512]
static constexpr size_t DBL_OFF  = XC_OFF   + (size_t)2 * ROWS * DI * 2;  // bf16 [4096][144]
static constexpr size_t DT_OFF   = DBL_OFF  + (size_t)2 * ROWS * NDBL * 2;// bf16 [2][2048][512]
static constexpr size_t Y_OFF    = DT_OFF   + (size_t)2 * ROWS * DI * 2;  // bf16 [2][2048][512]
static constexpr size_t XSSM_OFF = Y_OFF    + (size_t)2 * ROWS * DI * 2;  // f32  [2048][256]
static constexpr size_t X2_OFF   = XSSM_OFF + (size_t)ROWS * DM * 4;      // bf16 [2048][256]
static constexpr size_t FLAG_OFF = X2_OFF   + (size_t)ROWS * DM * 2;      // int
static constexpr size_t WB_OFF   = FLAG_OFF + 16;                         // bf16 weights
// converted-weight region (element offsets within WB):
static constexpr int WB_IWF = 0;        // f_in_w  [1024][256]
static constexpr int WB_IWB = 262144;   // b_in_w  [1024][256]
static constexpr int WB_XPF = 524288;   // f_xproj [144][512]
static constexpr int WB_XPB = 598016;   // b_xproj [144][512]
static constexpr int WB_OWF = 671744;   // f_out_w [256][512]
static constexpr int WB_OWB = 802816;   // b_out_w [256][512]
static constexpr int WB_W2  = 933888;   // w2      [256][256]
static constexpr int WB_DWF = 999424;   // f_dt_w  [512][16]
static constexpr int WB_DWB = 1007616;  // b_dt_w  [512][16]
static constexpr int WB_TOT = 1015808;
// total ws ≈ 27.3 MiB

// ---------------------------------------------------------------------------
// K0: dtype detect (f32 vs bf16).
// ---------------------------------------------------------------------------
__global__ void detect_kernel(const void* __restrict__ x, int* __restrict__ flag) {
  if (threadIdx.x == 0 && blockIdx.x == 0) {
    const u16* p = (const u16*)x;
    int f32 = 0;
    for (int i = 0; i < 512; i += 2) {
      float v = bf2f(p[i]);
      if (!(v > -1024.0f && v < 1024.0f)) f32 = 1;
    }
    *flag = f32;
  }
}

// ---------------------------------------------------------------------------
// K0b: convert all GEMM weights to bf16 into ws (identity if already bf16).
// ---------------------------------------------------------------------------
__global__ __launch_bounds__(256) void convert_kernel(
    const void* __restrict__ f_iw, const void* __restrict__ b_iw,
    const void* __restrict__ f_xp, const void* __restrict__ b_xp,
    const void* __restrict__ f_ow, const void* __restrict__ b_ow,
    const void* __restrict__ w2,   const void* __restrict__ f_dw,
    const void* __restrict__ b_dw, u16* __restrict__ wb,
    const int* __restrict__ flagp) {
  int f32 = *flagp;
  int i = blockIdx.x * 256 + threadIdx.x;
  if (i >= WB_TOT) return;
  const void* src; int off;
  if      (i < WB_IWB) { src = f_iw; off = i - WB_IWF; }
  else if (i < WB_XPF) { src = b_iw; off = i - WB_IWB; }
  else if (i < WB_XPB) { src = f_xp; off = i - WB_XPF; }
  else if (i < WB_OWF) { src = b_xp; off = i - WB_XPB; }
  else if (i < WB_OWB) { src = f_ow; off = i - WB_OWF; }
  else if (i < WB_W2)  { src = b_ow; off = i - WB_OWB; }
  else if (i < WB_DWF) { src = w2;   off = i - WB_W2;  }
  else if (i < WB_DWB) { src = f_dw; off = i - WB_DWF; }
  else                 { src = b_dw; off = i - WB_DWB; }
  wb[i] = f2bf(ldx(src, (size_t)off, f32));
}

// ---------------------------------------------------------------------------
// K1: LayerNorm over d_model=256 (input x -> bf16 ws). 1 block/row.
// ---------------------------------------------------------------------------
__global__ __launch_bounds__(256) void ln1_kernel(
    const void* __restrict__ x, const void* __restrict__ g,
    const void* __restrict__ b, u16* __restrict__ out,
    const int* __restrict__ flagp) {
  int f32 = *flagp;
  int row = blockIdx.x, tid = threadIdx.x;
  float v = ldx(x, (size_t)row * DM + tid, f32);
  float s = v, s2 = v * v;
  for (int o = 32; o; o >>= 1) { s += __shfl_xor(s, o); s2 += __shfl_xor(s2, o); }
  __shared__ float ls[4], ls2[4];
  int wid = tid >> 6;
  if ((tid & 63) == 0) { ls[wid] = s; ls2[wid] = s2; }
  __syncthreads();
  s  = ls[0] + ls[1] + ls[2] + ls[3];
  s2 = ls2[0] + ls2[1] + ls2[2] + ls2[3];
  float mu  = s * (1.0f / DM);
  float var = s2 * (1.0f / DM) - mu * mu;
  float r   = rsqrtf(var + 1e-5f);
  float xn  = (v - mu) * r * ldx(g, tid, f32) + ldx(b, tid, f32);
  out[(size_t)row * DM + tid] = f2bf(xn);
}

// same but f32 ws input (x_ssm)
__global__ __launch_bounds__(256) void ln2_kernel(
    const float* __restrict__ x, const void* __restrict__ g,
    const void* __restrict__ b, u16* __restrict__ out,
    const int* __restrict__ flagp) {
  int f32 = *flagp;
  int row = blockIdx.x, tid = threadIdx.x;
  float v = x[(size_t)row * DM + tid];
  float s = v, s2 = v * v;
  for (int o = 32; o; o >>= 1) { s += __shfl_xor(s, o); s2 += __shfl_xor(s2, o); }
  __shared__ float ls[4], ls2[4];
  int wid = tid >> 6;
  if ((tid & 63) == 0) { ls[wid] = s; ls2[wid] = s2; }
  __syncthreads();
  s  = ls[0] + ls[1] + ls[2] + ls[3];
  s2 = ls2[0] + ls2[1] + ls2[2] + ls2[3];
  float mu  = s * (1.0f / DM);
  float var = s2 * (1.0f / DM) - mu * mu;
  float r   = rsqrtf(var + 1e-5f);
  float xn  = (v - mu) * r * ldx(g, tid, f32) + ldx(b, tid, f32);
  out[(size_t)row * DM + tid] = f2bf(xn);
}

// ---------------------------------------------------------------------------
// K2: in-projection (MFMA). xz[dir][m][:] = xn[srow(m)] @ in_w.T  (K=256).
// grid (128, 4, 2), block 256. Wave: 16m x 64n.
// ---------------------------------------------------------------------------
__global__ __launch_bounds__(256) void inproj_kernel(
    const u16* __restrict__ xn, const u16* __restrict__ wb,
    u16* __restrict__ xz) {
  int dir  = blockIdx.z;
  int wave = threadIdx.x >> 6, lane = threadIdx.x & 63;
  int m0 = blockIdx.x * 16;
  int n0 = blockIdx.y * 256 + wave * 64;
  int lm = lane & 15, quad = lane >> 4;
  const short* W = (const short*)(wb + (dir ? WB_IWB : WB_IWF));
  const short* X = (const short*)xn;
  int m = m0 + lm;
  int bb = m >> 10, t = m & 1023;
  int srow = dir ? (bb * 1024 + (1023 - t)) : m;
  f32x4 acc[4] = {};
  for (int k0 = 0; k0 < DM; k0 += 32) {
    bf16x8 a = *(const bf16x8*)(X + (size_t)srow * DM + k0 + quad * 8);
#pragma unroll
    for (int c = 0; c < 4; ++c) {
      bf16x8 bf = *(const bf16x8*)(W + (size_t)(n0 + c * 16 + lm) * DM + k0 + quad * 8);
      acc[c] = MFMA(a, bf, acc[c]);
    }
  }
  u16* out = xz + (size_t)dir * ROWS * NXZ;
#pragma unroll
  for (int c = 0; c < 4; ++c)
#pragma unroll
    for (int r = 0; r < 4; ++r)
      out[(size_t)(m0 + quad * 4 + r) * NXZ + n0 + c * 16 + lm] = f2bf(acc[c][r]);
}

// ---------------------------------------------------------------------------
// K3: depthwise causal conv (width 4) + silu. 1 thread per (dir,row,d).
// ---------------------------------------------------------------------------
__global__ __launch_bounds__(256) void conv_kernel(
    const u16* __restrict__ xz, const void* __restrict__ f_cw,
    const void* __restrict__ f_cb, const void* __restrict__ b_cw,
    const void* __restrict__ b_cb, u16* __restrict__ xc,
    const int* __restrict__ flagp) {
  int f32 = *flagp;
  int idx = blockIdx.x * 256 + threadIdx.x;   // [0, 2*2048*512)
  int d   = idx & (DI - 1);
  int row = (idx >> 9) & (ROWS - 1);
  int dir = idx >> 20;
  int tpos = row & 1023;
  const void* cw = dir ? b_cw : f_cw;
  const void* cb = dir ? b_cb : f_cb;
  const u16* xi = xz + (size_t)dir * ROWS * NXZ;
  float s = ldx(cb, d, f32);
#pragma unroll
  for (int k = 0; k < 4; ++k) {
    int tt = tpos - 3 + k;
    if (tt >= 0)
      s += ldx(cw, d * 4 + k, f32) * bf2f(xi[(size_t)(row + k - 3) * NXZ + d]);
  }
  float sl = s / (1.0f + __expf(-s));
  xc[idx] = f2bf(sl);
}

// ---------------------------------------------------------------------------
// K4: x-projection (MFMA). dbl[m][n] = xc[m] @ xproj_w.T  (K=512).
// grid (64, 9), block 256 (4 waves along m). Wave: 16m x 16n.
// ---------------------------------------------------------------------------
__global__ __launch_bounds__(256) void xproj_kernel(
    const u16* __restrict__ xc, const u16* __restrict__ wb,
    u16* __restrict__ dbl) {
  int wave = threadIdx.x >> 6, lane = threadIdx.x & 63;
  int m0 = blockIdx.x * 64 + wave * 16;          // [0, 4096)
  int n0 = blockIdx.y * 16;
  int lm = lane & 15, quad = lane >> 4;
  const short* W = (const short*)(wb + ((m0 & 2048) ? WB_XPB : WB_XPF));
  const short* X = (const short*)xc;
  f32x4 acc = {};
  for (int k0 = 0; k0 < DI; k0 += 32) {
    bf16x8 a  = *(const bf16x8*)(X + (size_t)(m0 + lm) * DI + k0 + quad * 8);
    bf16x8 bf = *(const bf16x8*)(W + (size_t)(n0 + lm) * DI + k0 + quad * 8);
    acc = MFMA(a, bf, acc);
  }
#pragma unroll
  for (int r = 0; r < 4; ++r)
    dbl[(size_t)(m0 + quad * 4 + r) * NDBL + n0 + lm] = f2bf(acc[r]);
}

// ---------------------------------------------------------------------------
// K5: dt = softplus(dbl[:, :16] @ dt_w.T + dt_b). 1 thread/(m,n), vector loads.
// ---------------------------------------------------------------------------
__global__ __launch_bounds__(256) void dtproj_kernel(
    const u16* __restrict__ dbl, const u16* __restrict__ wb,
    const void* __restrict__ f_db, const void* __restrict__ b_db,
    u16* __restrict__ dt, const int* __restrict__ flagp) {
  int f32 = *flagp;
  int idx = blockIdx.x * 256 + threadIdx.x;   // [0, 4096*512)
  int n = idx & (DI - 1);
  int m = idx >> 9;                            // [0, 4096)
  int dir = m >> 11;
  const u16* dw = wb + (dir ? WB_DWB : WB_DWF) + n * 16;
  const u16* dr = dbl + (size_t)m * NDBL;
  float acc = ldx(dir ? b_db : f_db, n, f32);
  bf16x8 w0 = *(const bf16x8*)dw, w1 = *(const bf16x8*)(dw + 8);
  bf16x8 r0 = *(const bf16x8*)dr, r1 = *(const bf16x8*)(dr + 8);
#pragma unroll
  for (int k = 0; k < 8; ++k) acc += bf2f((u16)r0[k]) * bf2f((u16)w0[k]);
#pragma unroll
  for (int k = 0; k < 8; ++k) acc += bf2f((u16)r1[k]) * bf2f((u16)w1[k]);
  float sp = (acc > 20.0f) ? acc : log1pf(__expf(acc));
  dt[idx] = f2bf(sp);
}

// ---------------------------------------------------------------------------
// K6: selective scan, unrolled x8. One wave per (dir, b, d); lane = state.
// Per 8-step window: batch all loads (one waitcnt), register FMA chain for h,
// 8 independent butterflies, lane j stores step j.
// ---------------------------------------------------------------------------
__global__ __launch_bounds__(256) void scan_kernel(
    const u16* __restrict__ dt, const u16* __restrict__ xc,
    const u16* __restrict__ xz, const u16* __restrict__ dbl,
    const void* __restrict__ f_Al, const void* __restrict__ f_Dp,
    const void* __restrict__ b_Al, const void* __restrict__ b_Dp,
    u16* __restrict__ y, const int* __restrict__ flagp) {
  int f32 = *flagp;
  int gw   = blockIdx.x * 4 + (threadIdx.x >> 6);  // [0, 2048)
  int lane = threadIdx.x & 63;
  int d   = gw & (DI - 1);
  int bb  = (gw >> 9) & 1;
  int dir = gw >> 10;
  const void* Al = dir ? b_Al : f_Al;
  float A   = -__expf(ldx(Al, d * DS + lane, f32));
  float Dpd = ldx(dir ? b_Dp : f_Dp, d, f32);
  size_t rowbase = ((size_t)dir * ROWS + bb * 1024) * DI;
  size_t dblbase = ((size_t)dir * ROWS + bb * 1024) * NDBL;
  size_t zbase   = ((size_t)dir * ROWS + bb * 1024) * NXZ;
  float h = 0.0f;
  for (int t0 = 0; t0 < 1024; t0 += 8) {
    float dtv[8], xcv[8], zv[8], Bv[8], Cv[8], p[8];
#pragma unroll
    for (int j = 0; j < 8; ++j) {
      int t = t0 + j;
      dtv[j] = bf2f(dt[rowbase + (size_t)t * DI + d]);     // wave-uniform
      xcv[j] = bf2f(xc[rowbase + (size_t)t * DI + d]);     // wave-uniform
      zv[j]  = bf2f(xz[zbase + (size_t)t * NXZ + DI + d]); // wave-uniform
      Bv[j]  = bf2f(dbl[dblbase + (size_t)t * NDBL + 16 + lane]); // coalesced
      Cv[j]  = bf2f(dbl[dblbase + (size_t)t * NDBL + 80 + lane]); // coalesced
    }
#pragma unroll
    for (int j = 0; j < 8; ++j) {
      h = __expf(dtv[j] * A) * h + dtv[j] * Bv[j] * xcv[j];
      p[j] = h * Cv[j];
    }
#pragma unroll
    for (int j = 0; j < 8; ++j)
#pragma unroll
      for (int o = 32; o; o >>= 1) p[j] += __shfl_xor(p[j], o);
    // lane j handles timestep t0+j (xcv/zv are uniform, p[j] is in all lanes)
    float myp = p[0], myxc = xcv[0], myz = zv[0];
#pragma unroll
    for (int j = 1; j < 8; ++j) {
      myp  = (lane == j) ? p[j]   : myp;
      myxc = (lane == j) ? xcv[j] : myxc;
      myz  = (lane == j) ? zv[j]  : myz;
    }
    if (lane < 8) {
      float yv = (myp + myxc * Dpd) * (myz / (1.0f + __expf(-myz)));
      y[rowbase + (size_t)(t0 + lane) * DI + d] = f2bf(yv);
    }
  }
}

// ---------------------------------------------------------------------------
// K7: out-projection (MFMA) + combine dirs. K=512 per dir.
// grid 128, block 256 (4 waves along n). Wave: 16m x 64n.
// ---------------------------------------------------------------------------
__global__ __launch_bounds__(256) void outproj_kernel(
    const u16* __restrict__ y, const u16* __restrict__ wb,
    float* __restrict__ xssm) {
  int wave = threadIdx.x >> 6, lane = threadIdx.x & 63;
  int m0 = blockIdx.x * 16;
  int n0 = wave * 64;
  int lm = lane & 15, quad = lane >> 4;
  const short* Y = (const short*)y;
  int m  = m0 + lm;
  int bb = m >> 10, t = m & 1023;
  int srow_b = ROWS + bb * 1024 + (1023 - t);
  f32x4 acc[4] = {};
  {
    const short* W = (const short*)(wb + WB_OWF);
    for (int k0 = 0; k0 < DI; k0 += 32) {
      bf16x8 a = *(const bf16x8*)(Y + (size_t)m * DI + k0 + quad * 8);
#pragma unroll
      for (int c = 0; c < 4; ++c) {
        bf16x8 bf = *(const bf16x8*)(W + (size_t)(n0 + c * 16 + lm) * DI + k0 + quad * 8);
        acc[c] = MFMA(a, bf, acc[c]);
      }
    }
  }
  {
    const short* W = (const short*)(wb + WB_OWB);
    for (int k0 = 0; k0 < DI; k0 += 32) {
      bf16x8 a = *(const bf16x8*)(Y + (size_t)srow_b * DI + k0 + quad * 8);
#pragma unroll
      for (int c = 0; c < 4; ++c) {
        bf16x8 bf = *(const bf16x8*)(W + (size_t)(n0 + c * 16 + lm) * DI + k0 + quad * 8);
        acc[c] = MFMA(a, bf, acc[c]);
      }
    }
  }
#pragma unroll
  for (int c = 0; c < 4; ++c)
#pragma unroll
    for (int r = 0; r < 4; ++r)
      xssm[(size_t)(m0 + quad * 4 + r) * DM + n0 + c * 16 + lm] = acc[c][r];
}

// ---------------------------------------------------------------------------
// K9: out = gelu_exact(x2 @ w2.T + b2) (MFMA). grid 128, block 256.
// ---------------------------------------------------------------------------
__global__ __launch_bounds__(256) void final_kernel(
    const u16* __restrict__ x2, const u16* __restrict__ wb,
    const void* __restrict__ b2, void* __restrict__ out,
    const int* __restrict__ flagp) {
  int f32 = *flagp;
  int wave = threadIdx.x >> 6, lane = threadIdx.x & 63;
  int m0 = blockIdx.x * 16;
  int n0 = wave * 64;
  int lm = lane & 15, quad = lane >> 4;
  const short* X = (const short*)x2;
  const short* W = (const short*)(wb + WB_W2);
  f32x4 acc[4] = {};
  for (int k0 = 0; k0 < DM; k0 += 32) {
    bf16x8 a = *(const bf16x8*)(X + (size_t)(m0 + lm) * DM + k0 + quad * 8);
#pragma unroll
    for (int c = 0; c < 4; ++c) {
      bf16x8 bf = *(const bf16x8*)(W + (size_t)(n0 + c * 16 + lm) * DM + k0 + quad * 8);
      acc[c] = MFMA(a, bf, acc[c]);
    }
  }
#pragma unroll
  for (int c = 0; c < 4; ++c)
#pragma unroll
    for (int r = 0; r < 4; ++r) {
      int col = n0 + c * 16 + lm;
      float v = acc[c][r] + ldx(b2, col, f32);
      float g = 0.5f * v * (1.0f + erff(v * 0.70710678118654752f));
      size_t o = (size_t)(m0 + quad * 4 + r) * DM + col;
      if (f32) ((float*)out)[o] = g;
      else     ((u16*)out)[o]   = f2bf(g);
    }
}

// ---------------------------------------------------------------------------
extern "C" void kernel_launch(void* const* d_in, const int* in_sizes, int n_in,
                              void* d_out, int out_size, void* d_ws, size_t ws_size,
                              hipStream_t stream) {
  const void* x        = d_in[0];
  const void* f_in_w   = d_in[1];
  const void* f_conv_w = d_in[2];
  const void* f_conv_b = d_in[3];
  const void* f_xproj  = d_in[4];
  const void* f_dt_w   = d_in[5];
  const void* f_dt_b   = d_in[6];
  const void* f_A_log  = d_in[7];
  const void* f_Dp     = d_in[8];
  const void* f_out_w  = d_in[9];
  const void* b_in_w   = d_in[10];
  const void* b_conv_w = d_in[11];
  const void* b_conv_b = d_in[12];
  const void* b_xproj  = d_in[13];
  const void* b_dt_w   = d_in[14];
  const void* b_dt_b   = d_in[15];
  const void* b_A_log  = d_in[16];
  const void* b_Dp     = d_in[17];
  const void* b_out_w  = d_in[18];
  const void* ln1_g    = d_in[19];
  const void* ln1_b    = d_in[20];
  const void* ln2_g    = d_in[21];
  const void* ln2_b    = d_in[22];
  const void* w2       = d_in[23];
  const void* b2       = d_in[24];

  char* ws = (char*)d_ws;
  u16*   xn   = (u16*)(ws + XN_OFF);
  u16*   xz   = (u16*)(ws + XZ_OFF);
  u16*   xc   = (u16*)(ws + XC_OFF);
  u16*   dbl  = (u16*)(ws + DBL_OFF);
  u16*   dt   = (u16*)(ws + DT_OFF);
  u16*   y    = (u16*)(ws + Y_OFF);
  float* xssm = (float*)(ws + XSSM_OFF);
  u16*   x2   = (u16*)(ws + X2_OFF);
  int*   flag = (int*)(ws + FLAG_OFF);
  u16*   wb   = (u16*)(ws + WB_OFF);

  detect_kernel<<<1, 64, 0, stream>>>(x, flag);
  convert_kernel<<<(WB_TOT + 255) / 256, 256, 0, stream>>>(
      f_in_w, b_in_w, f_xproj, b_xproj, f_out_w, b_out_w, w2, f_dt_w, b_dt_w,
      wb, flag);
  ln1_kernel<<<ROWS, 256, 0, stream>>>(x, ln1_g, ln1_b, xn, flag);
  inproj_kernel<<<dim3(ROWS / 16, 4, 2), 256, 0, stream>>>(xn, wb, xz);
  conv_kernel<<<(2 * ROWS * DI) / 256, 256, 0, stream>>>(
      xz, f_conv_w, f_conv_b, b_conv_w, b_conv_b, xc, flag);
  xproj_kernel<<<dim3(64, 9), 256, 0, stream>>>(xc, wb, dbl);
  dtproj_kernel<<<(2 * ROWS * DI) / 256, 256, 0, stream>>>(
      dbl, wb, f_dt_b, b_dt_b, dt, flag);
  scan_kernel<<<512, 256, 0, stream>>>(dt, xc, xz, dbl, f_A_log, f_Dp, b_A_log, b_Dp, y, flag);
  outproj_kernel<<<ROWS / 16, 256, 0, stream>>>(y, wb, xssm);
  ln2_kernel<<<ROWS, 256, 0, stream>>>(xssm, ln2_g, ln2_b, x2, flag);
  final_kernel<<<ROWS / 16, 256, 0, stream>>>(x2, wb, b2, d_out, flag);
}

// Round 6
// 365.932 us; speedup vs baseline: 14.0534x; 1.1181x over previous
//
#include <hip/hip_runtime.h>

// ---------------------------------------------------------------------------
// BiMambaEncoderBlock on MI355X (gfx950). fp32 accumulate, bf16 intermediates.
// B=2, S=1024, D_MODEL=256, D_INNER=512, D_STATE=64, DT_RANK=16, D_CONV=4.
// Round 6: scan split into two passes over 4 time-chunks (chunk transfer is
// h_out = P*h_in + b, P = prod(dA) per lane) -> 4x wave parallelism; 27-op
// butterfly (3+3 stages with register transpose); dbl kept f32; conv 8-wide.
// ---------------------------------------------------------------------------

typedef unsigned short u16;
typedef short bf16x8 __attribute__((ext_vector_type(8)));   // 8 bf16 = 4 VGPRs
typedef float f32x4  __attribute__((ext_vector_type(4)));

#define MFMA(a, b, c) __builtin_amdgcn_mfma_f32_16x16x32_bf16((a), (b), (c), 0, 0, 0)

static constexpr int ROWS = 2048;   // B*S
static constexpr int DM   = 256;    // d_model
static constexpr int DI   = 512;    // d_inner
static constexpr int NXZ  = 1024;   // 2*d_inner
static constexpr int NDBL = 144;    // dt_rank + 2*d_state
static constexpr int DS   = 64;     // d_state

__device__ __forceinline__ float bf2f(u16 u) {
  union { unsigned u32; float f; } v; v.u32 = ((unsigned)u) << 16; return v.f;
}
__device__ __forceinline__ u16 f2bf(float f) {
  union { float f; unsigned u; } v; v.f = f;
  unsigned r = v.u + 0x7FFFu + ((v.u >> 16) & 1u);   // RNE (finite inputs)
  return (u16)(r >> 16);
}
__device__ __forceinline__ float ldx(const void* p, size_t i, int f32) {
  return f32 ? ((const float*)p)[i] : bf2f(((const u16*)p)[i]);
}

// ---- workspace layout (bytes) ----
static constexpr size_t XN_OFF   = 0;                                   // bf16 [2048][256]
static constexpr size_t XZ_OFF   = 1048576;                             // bf16 [2][2048][1024]
static constexpr size_t XC_OFF   = 9437184;                             // bf16 [2][2048][512]
static constexpr size_t DBL_OFF  = 13631488;                            // f32  [4096][144]
static constexpr size_t DT_OFF   = 15990784;                            // bf16 [2][2048][512]
static constexpr size_t Y_OFF    = 20185088;                            // bf16 [2][2048][512]
static constexpr size_t XSSM_OFF = 24379392;                            // f32  [2048][256]
static constexpr size_t X2_OFF   = 26476544;                            // bf16 [2048][256]
static constexpr size_t PCH_OFF  = 27525120;                            // f32  [2048][3][64]
static constexpr size_t BCH_OFF  = 29097984;                            // f32  [2048][3][64]
static constexpr size_t FLAG_OFF = 30670848;                            // int
static constexpr size_t WB_OFF   = 30670864;                            // bf16 weights
// converted-weight region (element offsets within WB):
static constexpr int WB_IWF = 0;        // f_in_w  [1024][256]
static constexpr int WB_IWB = 262144;   // b_in_w  [1024][256]
static constexpr int WB_XPF = 524288;   // f_xproj [144][512]
static constexpr int WB_XPB = 598016;   // b_xproj [144][512]
static constexpr int WB_OWF = 671744;   // f_out_w [256][512]
static constexpr int WB_OWB = 802816;   // b_out_w [256][512]
static constexpr int WB_W2  = 933888;   // w2      [256][256]
static constexpr int WB_DWF = 999424;   // f_dt_w  [512][16]
static constexpr int WB_DWB = 1007616;  // b_dt_w  [512][16]
static constexpr int WB_TOT = 1015808;
// total ws ≈ 31.2 MiB

// ---------------------------------------------------------------------------
// K0: dtype detect (f32 vs bf16).
// ---------------------------------------------------------------------------
__global__ void detect_kernel(const void* __restrict__ x, int* __restrict__ flag) {
  if (threadIdx.x == 0 && blockIdx.x == 0) {
    const u16* p = (const u16*)x;
    int f32 = 0;
    for (int i = 0; i < 512; i += 2) {
      float v = bf2f(p[i]);
      if (!(v > -1024.0f && v < 1024.0f)) f32 = 1;
    }
    *flag = f32;
  }
}

// ---------------------------------------------------------------------------
// K0b: convert all GEMM weights to bf16 into ws (identity if already bf16).
// ---------------------------------------------------------------------------
__global__ __launch_bounds__(256) void convert_kernel(
    const void* __restrict__ f_iw, const void* __restrict__ b_iw,
    const void* __restrict__ f_xp, const void* __restrict__ b_xp,
    const void* __restrict__ f_ow, const void* __restrict__ b_ow,
    const void* __restrict__ w2,   const void* __restrict__ f_dw,
    const void* __restrict__ b_dw, u16* __restrict__ wb,
    const int* __restrict__ flagp) {
  int f32 = *flagp;
  int i = blockIdx.x * 256 + threadIdx.x;
  if (i >= WB_TOT) return;
  const void* src; int off;
  if      (i < WB_IWB) { src = f_iw; off = i - WB_IWF; }
  else if (i < WB_XPF) { src = b_iw; off = i - WB_IWB; }
  else if (i < WB_XPB) { src = f_xp; off = i - WB_XPF; }
  else if (i < WB_OWF) { src = b_xp; off = i - WB_XPB; }
  else if (i < WB_OWB) { src = f_ow; off = i - WB_OWF; }
  else if (i < WB_W2)  { src = b_ow; off = i - WB_OWB; }
  else if (i < WB_DWF) { src = w2;   off = i - WB_W2;  }
  else if (i < WB_DWB) { src = f_dw; off = i - WB_DWF; }
  else                 { src = b_dw; off = i - WB_DWB; }
  wb[i] = f2bf(ldx(src, (size_t)off, f32));
}

// ---------------------------------------------------------------------------
// K1: LayerNorm over d_model=256 (input x -> bf16 ws). 1 block/row.
// ---------------------------------------------------------------------------
__global__ __launch_bounds__(256) void ln1_kernel(
    const void* __restrict__ x, const void* __restrict__ g,
    const void* __restrict__ b, u16* __restrict__ out,
    const int* __restrict__ flagp) {
  int f32 = *flagp;
  int row = blockIdx.x, tid = threadIdx.x;
  float v = ldx(x, (size_t)row * DM + tid, f32);
  float s = v, s2 = v * v;
  for (int o = 32; o; o >>= 1) { s += __shfl_xor(s, o); s2 += __shfl_xor(s2, o); }
  __shared__ float ls[4], ls2[4];
  int wid = tid >> 6;
  if ((tid & 63) == 0) { ls[wid] = s; ls2[wid] = s2; }
  __syncthreads();
  s  = ls[0] + ls[1] + ls[2] + ls[3];
  s2 = ls2[0] + ls2[1] + ls2[2] + ls2[3];
  float mu  = s * (1.0f / DM);
  float var = s2 * (1.0f / DM) - mu * mu;
  float r   = rsqrtf(var + 1e-5f);
  float xn  = (v - mu) * r * ldx(g, tid, f32) + ldx(b, tid, f32);
  out[(size_t)row * DM + tid] = f2bf(xn);
}

// same but f32 ws input (x_ssm)
__global__ __launch_bounds__(256) void ln2_kernel(
    const float* __restrict__ x, const void* __restrict__ g,
    const void* __restrict__ b, u16* __restrict__ out,
    const int* __restrict__ flagp) {
  int f32 = *flagp;
  int row = blockIdx.x, tid = threadIdx.x;
  float v = x[(size_t)row * DM + tid];
  float s = v, s2 = v * v;
  for (int o = 32; o; o >>= 1) { s += __shfl_xor(s, o); s2 += __shfl_xor(s2, o); }
  __shared__ float ls[4], ls2[4];
  int wid = tid >> 6;
  if ((tid & 63) == 0) { ls[wid] = s; ls2[wid] = s2; }
  __syncthreads();
  s  = ls[0] + ls[1] + ls[2] + ls[3];
  s2 = ls2[0] + ls2[1] + ls2[2] + ls2[3];
  float mu  = s * (1.0f / DM);
  float var = s2 * (1.0f / DM) - mu * mu;
  float r   = rsqrtf(var + 1e-5f);
  float xn  = (v - mu) * r * ldx(g, tid, f32) + ldx(b, tid, f32);
  out[(size_t)row * DM + tid] = f2bf(xn);
}

// ---------------------------------------------------------------------------
// K2: in-projection (MFMA). xz[dir][m][:] = xn[srow(m)] @ in_w.T  (K=256).
// grid (128, 4, 2), block 256. Wave: 16m x 64n.
// ---------------------------------------------------------------------------
__global__ __launch_bounds__(256) void inproj_kernel(
    const u16* __restrict__ xn, const u16* __restrict__ wb,
    u16* __restrict__ xz) {
  int dir  = blockIdx.z;
  int wave = threadIdx.x >> 6, lane = threadIdx.x & 63;
  int m0 = blockIdx.x * 16;
  int n0 = blockIdx.y * 256 + wave * 64;
  int lm = lane & 15, quad = lane >> 4;
  const short* W = (const short*)(wb + (dir ? WB_IWB : WB_IWF));
  const short* X = (const short*)xn;
  int m = m0 + lm;
  int bb = m >> 10, t = m & 1023;
  int srow = dir ? (bb * 1024 + (1023 - t)) : m;
  f32x4 acc[4] = {};
  for (int k0 = 0; k0 < DM; k0 += 32) {
    bf16x8 a = *(const bf16x8*)(X + (size_t)srow * DM + k0 + quad * 8);
#pragma unroll
    for (int c = 0; c < 4; ++c) {
      bf16x8 bf = *(const bf16x8*)(W + (size_t)(n0 + c * 16 + lm) * DM + k0 + quad * 8);
      acc[c] = MFMA(a, bf, acc[c]);
    }
  }
  u16* out = xz + (size_t)dir * ROWS * NXZ;
#pragma unroll
  for (int c = 0; c < 4; ++c)
#pragma unroll
    for (int r = 0; r < 4; ++r)
      out[(size_t)(m0 + quad * 4 + r) * NXZ + n0 + c * 16 + lm] = f2bf(acc[c][r]);
}

// ---------------------------------------------------------------------------
// K3: depthwise causal conv (width 4) + silu, 8 channels/thread (bf16x8).
// grid 1024, block 256; thread = (dir, row, d-group-of-8).
// ---------------------------------------------------------------------------
__global__ __launch_bounds__(256) void conv_kernel(
    const u16* __restrict__ xz, const void* __restrict__ f_cw,
    const void* __restrict__ f_cb, const void* __restrict__ b_cw,
    const void* __restrict__ b_cb, u16* __restrict__ xc,
    const int* __restrict__ flagp) {
  int f32 = *flagp;
  int idx = blockIdx.x * 256 + threadIdx.x;   // [0, 2*2048*64)
  int g   = idx & 63;
  int row = (idx >> 6) & (ROWS - 1);
  int dir = idx >> 17;
  int tpos = row & 1023;
  int d0 = g * 8;
  const void* cw = dir ? b_cw : f_cw;
  const void* cb = dir ? b_cb : f_cb;
  const u16* xi = xz + (size_t)dir * ROWS * NXZ;
  float s[8];
#pragma unroll
  for (int e = 0; e < 8; ++e) s[e] = ldx(cb, d0 + e, f32);
#pragma unroll
  for (int k = 0; k < 4; ++k) {
    int tt = tpos - 3 + k;
    if (tt >= 0) {
      bf16x8 xv = *(const bf16x8*)(xi + (size_t)(row + k - 3) * NXZ + d0);
#pragma unroll
      for (int e = 0; e < 8; ++e)
        s[e] += ldx(cw, (d0 + e) * 4 + k, f32) * bf2f((u16)xv[e]);
    }
  }
  bf16x8 ov;
#pragma unroll
  for (int e = 0; e < 8; ++e) {
    float sl = s[e] / (1.0f + __expf(-s[e]));
    ov[e] = (short)f2bf(sl);
  }
  *(bf16x8*)(xc + ((size_t)dir * ROWS + row) * DI + d0) = ov;
}

// ---------------------------------------------------------------------------
// K4: x-projection (MFMA). dbl[m][n] = xc[m] @ xproj_w.T  (K=512), f32 out.
// grid (64, 9), block 256 (4 waves along m). Wave: 16m x 16n.
// ---------------------------------------------------------------------------
__global__ __launch_bounds__(256) void xproj_kernel(
    const u16* __restrict__ xc, const u16* __restrict__ wb,
    float* __restrict__ dbl) {
  int wave = threadIdx.x >> 6, lane = threadIdx.x & 63;
  int m0 = blockIdx.x * 64 + wave * 16;          // [0, 4096)
  int n0 = blockIdx.y * 16;
  int lm = lane & 15, quad = lane >> 4;
  const short* W = (const short*)(wb + ((m0 & 2048) ? WB_XPB : WB_XPF));
  const short* X = (const short*)xc;
  f32x4 acc = {};
  for (int k0 = 0; k0 < DI; k0 += 32) {
    bf16x8 a  = *(const bf16x8*)(X + (size_t)(m0 + lm) * DI + k0 + quad * 8);
    bf16x8 bf = *(const bf16x8*)(W + (size_t)(n0 + lm) * DI + k0 + quad * 8);
    acc = MFMA(a, bf, acc);
  }
#pragma unroll
  for (int r = 0; r < 4; ++r)
    dbl[(size_t)(m0 + quad * 4 + r) * NDBL + n0 + lm] = acc[r];
}

// ---------------------------------------------------------------------------
// K5: dt = softplus(dbl[:, :16] @ dt_w.T + dt_b). 1 thread/(m,n).
// ---------------------------------------------------------------------------
__global__ __launch_bounds__(256) void dtproj_kernel(
    const float* __restrict__ dbl, const u16* __restrict__ wb,
    const void* __restrict__ f_db, const void* __restrict__ b_db,
    u16* __restrict__ dt, const int* __restrict__ flagp) {
  int f32 = *flagp;
  int idx = blockIdx.x * 256 + threadIdx.x;   // [0, 4096*512)
  int n = idx & (DI - 1);
  int m = idx >> 9;                            // [0, 4096)
  int dir = m >> 11;
  const u16* dw = wb + (dir ? WB_DWB : WB_DWF) + n * 16;
  const float* dr = dbl + (size_t)m * NDBL;
  float acc = ldx(dir ? b_db : f_db, n, f32);
  bf16x8 w0 = *(const bf16x8*)dw, w1 = *(const bf16x8*)(dw + 8);
#pragma unroll
  for (int k = 0; k < 8; ++k) acc += dr[k] * bf2f((u16)w0[k]);
#pragma unroll
  for (int k = 0; k < 8; ++k) acc += dr[8 + k] * bf2f((u16)w1[k]);
  float sp = (acc > 20.0f) ? acc : log1pf(__expf(acc));
  dt[idx] = f2bf(sp);
}

// ---------------------------------------------------------------------------
// K6a: scan pass 1 — per-chunk (P, b) for chunks 0..2, h-only recurrence.
// grid (512, 3), block 256. Wave = (dir,b,d), chunk = blockIdx.y.
// ---------------------------------------------------------------------------
__global__ __launch_bounds__(256) void scan_pass1(
    const u16* __restrict__ dt, const u16* __restrict__ xc,
    const float* __restrict__ dbl,
    const void* __restrict__ f_Al, const void* __restrict__ b_Al,
    float* __restrict__ Pch, float* __restrict__ Bch,
    const int* __restrict__ flagp) {
  int f32 = *flagp;
  int gw   = blockIdx.x * 4 + (threadIdx.x >> 6);  // [0, 2048)
  int c    = blockIdx.y;                            // 0..2
  int lane = threadIdx.x & 63;
  int d = gw & (DI - 1), bb = (gw >> 9) & 1, dir = gw >> 10;
  float A = -__expf(ldx(dir ? b_Al : f_Al, d * DS + lane, f32));
  size_t rowbase = ((size_t)dir * ROWS + bb * 1024) * DI;
  size_t dblbase = ((size_t)dir * ROWS + bb * 1024) * (size_t)NDBL;
  float h = 0.0f, P = 1.0f;
  int tbeg = c * 256;
  for (int t0 = tbeg; t0 < tbeg + 256; t0 += 8) {
    float dtv[8], xcv[8], Bv[8];
#pragma unroll
    for (int j = 0; j < 8; ++j) {
      int t = t0 + j;
      dtv[j] = bf2f(dt[rowbase + (size_t)t * DI + d]);
      xcv[j] = bf2f(xc[rowbase + (size_t)t * DI + d]);
      Bv[j]  = dbl[dblbase + (size_t)t * NDBL + 16 + lane];
    }
#pragma unroll
    for (int j = 0; j < 8; ++j) {
      float dA = __expf(dtv[j] * A);
      h = dA * h + dtv[j] * Bv[j] * xcv[j];
      P *= dA;
    }
  }
  size_t o = ((size_t)gw * 3 + c) * 64 + lane;
  Pch[o] = P;
  Bch[o] = h;
}

// ---------------------------------------------------------------------------
// K6b: scan pass 2 — 4 chunks in parallel; h_in composed from (P,b) of
// preceding chunks; full per-step y with 27-shuffle reduction.
// grid (512, 4), block 256.
// ---------------------------------------------------------------------------
__global__ __launch_bounds__(256) void scan_pass2(
    const u16* __restrict__ dt, const u16* __restrict__ xc,
    const u16* __restrict__ xz, const float* __restrict__ dbl,
    const void* __restrict__ f_Al, const void* __restrict__ f_Dp,
    const void* __restrict__ b_Al, const void* __restrict__ b_Dp,
    const float* __restrict__ Pch, const float* __restrict__ Bch,
    u16* __restrict__ y, const int* __restrict__ flagp) {
  int f32 = *flagp;
  int gw   = blockIdx.x * 4 + (threadIdx.x >> 6);  // [0, 2048)
  int c    = blockIdx.y;                            // 0..3
  int lane = threadIdx.x & 63;
  int grp  = lane >> 3;                             // value index carried
  int d = gw & (DI - 1), bb = (gw >> 9) & 1, dir = gw >> 10;
  float A   = -__expf(ldx(dir ? b_Al : f_Al, d * DS + lane, f32));
  float Dpd = ldx(dir ? b_Dp : f_Dp, d, f32);
  size_t rowbase = ((size_t)dir * ROWS + bb * 1024) * DI;
  size_t dblbase = ((size_t)dir * ROWS + bb * 1024) * (size_t)NDBL;
  size_t zbase   = ((size_t)dir * ROWS + bb * 1024) * NXZ;
  float h = 0.0f;
  for (int cc = 0; cc < c; ++cc) {
    size_t o = ((size_t)gw * 3 + cc) * 64 + lane;
    h = Pch[o] * h + Bch[o];
  }
  int tbeg = c * 256;
  for (int t0 = tbeg; t0 < tbeg + 256; t0 += 8) {
    float dtv[8], xcv[8], zv[8], Bv[8], Cv[8], p[8];
#pragma unroll
    for (int j = 0; j < 8; ++j) {
      int t = t0 + j;
      dtv[j] = bf2f(dt[rowbase + (size_t)t * DI + d]);     // wave-uniform
      xcv[j] = bf2f(xc[rowbase + (size_t)t * DI + d]);     // wave-uniform
      zv[j]  = bf2f(xz[zbase + (size_t)t * NXZ + DI + d]); // wave-uniform
      Bv[j]  = dbl[dblbase + (size_t)t * NDBL + 16 + lane]; // coalesced
      Cv[j]  = dbl[dblbase + (size_t)t * NDBL + 80 + lane]; // coalesced
    }
#pragma unroll
    for (int j = 0; j < 8; ++j) {
      h = __expf(dtv[j] * A) * h + dtv[j] * Bv[j] * xcv[j];
      p[j] = h * Cv[j];
    }
    // stage A: residue sums over lanes ≡ (lane&7) mod 8
#pragma unroll
    for (int j = 0; j < 8; ++j) {
      p[j] += __shfl_xor(p[j], 8);
      p[j] += __shfl_xor(p[j], 16);
      p[j] += __shfl_xor(p[j], 32);
    }
    // register transpose: lane carries value index grp = lane>>3
    float v = p[0], mxc = xcv[0], mz = zv[0];
#pragma unroll
    for (int j = 1; j < 8; ++j) {
      bool sel = (grp == j);
      v   = sel ? p[j]   : v;
      mxc = sel ? xcv[j] : mxc;
      mz  = sel ? zv[j]  : mz;
    }
    // stage B: sum the 8 residues within each 8-lane group
    v += __shfl_xor(v, 1);
    v += __shfl_xor(v, 2);
    v += __shfl_xor(v, 4);
    if ((lane & 7) == 0) {
      float yv = (v + mxc * Dpd) * (mz / (1.0f + __expf(-mz)));
      y[rowbase + (size_t)(t0 + grp) * DI + d] = f2bf(yv);
    }
  }
}

// ---------------------------------------------------------------------------
// K7: out-projection (MFMA) + combine dirs. K=512 per dir.
// grid 128, block 256 (4 waves along n). Wave: 16m x 64n.
// ---------------------------------------------------------------------------
__global__ __launch_bounds__(256) void outproj_kernel(
    const u16* __restrict__ y, const u16* __restrict__ wb,
    float* __restrict__ xssm) {
  int wave = threadIdx.x >> 6, lane = threadIdx.x & 63;
  int m0 = blockIdx.x * 16;
  int n0 = wave * 64;
  int lm = lane & 15, quad = lane >> 4;
  const short* Y = (const short*)y;
  int m  = m0 + lm;
  int bb = m >> 10, t = m & 1023;
  int srow_b = ROWS + bb * 1024 + (1023 - t);
  f32x4 acc[4] = {};
  {
    const short* W = (const short*)(wb + WB_OWF);
    for (int k0 = 0; k0 < DI; k0 += 32) {
      bf16x8 a = *(const bf16x8*)(Y + (size_t)m * DI + k0 + quad * 8);
#pragma unroll
      for (int c = 0; c < 4; ++c) {
        bf16x8 bf = *(const bf16x8*)(W + (size_t)(n0 + c * 16 + lm) * DI + k0 + quad * 8);
        acc[c] = MFMA(a, bf, acc[c]);
      }
    }
  }
  {
    const short* W = (const short*)(wb + WB_OWB);
    for (int k0 = 0; k0 < DI; k0 += 32) {
      bf16x8 a = *(const bf16x8*)(Y + (size_t)srow_b * DI + k0 + quad * 8);
#pragma unroll
      for (int c = 0; c < 4; ++c) {
        bf16x8 bf = *(const bf16x8*)(W + (size_t)(n0 + c * 16 + lm) * DI + k0 + quad * 8);
        acc[c] = MFMA(a, bf, acc[c]);
      }
    }
  }
#pragma unroll
  for (int c = 0; c < 4; ++c)
#pragma unroll
    for (int r = 0; r < 4; ++r)
      xssm[(size_t)(m0 + quad * 4 + r) * DM + n0 + c * 16 + lm] = acc[c][r];
}

// ---------------------------------------------------------------------------
// K9: out = gelu_exact(x2 @ w2.T + b2) (MFMA). grid 128, block 256.
// ---------------------------------------------------------------------------
__global__ __launch_bounds__(256) void final_kernel(
    const u16* __restrict__ x2, const u16* __restrict__ wb,
    const void* __restrict__ b2, void* __restrict__ out,
    const int* __restrict__ flagp) {
  int f32 = *flagp;
  int wave = threadIdx.x >> 6, lane = threadIdx.x & 63;
  int m0 = blockIdx.x * 16;
  int n0 = wave * 64;
  int lm = lane & 15, quad = lane >> 4;
  const short* X = (const short*)x2;
  const short* W = (const short*)(wb + WB_W2);
  f32x4 acc[4] = {};
  for (int k0 = 0; k0 < DM; k0 += 32) {
    bf16x8 a = *(const bf16x8*)(X + (size_t)(m0 + lm) * DM + k0 + quad * 8);
#pragma unroll
    for (int c = 0; c < 4; ++c) {
      bf16x8 bf = *(const bf16x8*)(W + (size_t)(n0 + c * 16 + lm) * DM + k0 + quad * 8);
      acc[c] = MFMA(a, bf, acc[c]);
    }
  }
#pragma unroll
  for (int c = 0; c < 4; ++c)
#pragma unroll
    for (int r = 0; r < 4; ++r) {
      int col = n0 + c * 16 + lm;
      float v = acc[c][r] + ldx(b2, col, f32);
      float g = 0.5f * v * (1.0f + erff(v * 0.70710678118654752f));
      size_t o = (size_t)(m0 + quad * 4 + r) * DM + col;
      if (f32) ((float*)out)[o] = g;
      else     ((u16*)out)[o]   = f2bf(g);
    }
}

// ---------------------------------------------------------------------------
extern "C" void kernel_launch(void* const* d_in, const int* in_sizes, int n_in,
                              void* d_out, int out_size, void* d_ws, size_t ws_size,
                              hipStream_t stream) {
  const void* x        = d_in[0];
  const void* f_in_w   = d_in[1];
  const void* f_conv_w = d_in[2];
  const void* f_conv_b = d_in[3];
  const void* f_xproj  = d_in[4];
  const void* f_dt_w   = d_in[5];
  const void* f_dt_b   = d_in[6];
  const void* f_A_log  = d_in[7];
  const void* f_Dp     = d_in[8];
  const void* f_out_w  = d_in[9];
  const void* b_in_w   = d_in[10];
  const void* b_conv_w = d_in[11];
  const void* b_conv_b = d_in[12];
  const void* b_xproj  = d_in[13];
  const void* b_dt_w   = d_in[14];
  const void* b_dt_b   = d_in[15];
  const void* b_A_log  = d_in[16];
  const void* b_Dp     = d_in[17];
  const void* b_out_w  = d_in[18];
  const void* ln1_g    = d_in[19];
  const void* ln1_b    = d_in[20];
  const void* ln2_g    = d_in[21];
  const void* ln2_b    = d_in[22];
  const void* w2       = d_in[23];
  const void* b2       = d_in[24];

  char* ws = (char*)d_ws;
  u16*   xn   = (u16*)(ws + XN_OFF);
  u16*   xz   = (u16*)(ws + XZ_OFF);
  u16*   xc   = (u16*)(ws + XC_OFF);
  float* dbl  = (float*)(ws + DBL_OFF);
  u16*   dt   = (u16*)(ws + DT_OFF);
  u16*   y    = (u16*)(ws + Y_OFF);
  float* xssm = (float*)(ws + XSSM_OFF);
  u16*   x2   = (u16*)(ws + X2_OFF);
  float* Pch  = (float*)(ws + PCH_OFF);
  float* Bch  = (float*)(ws + BCH_OFF);
  int*   flag = (int*)(ws + FLAG_OFF);
  u16*   wb   = (u16*)(ws + WB_OFF);

  detect_kernel<<<1, 64, 0, stream>>>(x, flag);
  convert_kernel<<<(WB_TOT + 255) / 256, 256, 0, stream>>>(
      f_in_w, b_in_w, f_xproj, b_xproj, f_out_w, b_out_w, w2, f_dt_w, b_dt_w,
      wb, flag);
  ln1_kernel<<<ROWS, 256, 0, stream>>>(x, ln1_g, ln1_b, xn, flag);
  inproj_kernel<<<dim3(ROWS / 16, 4, 2), 256, 0, stream>>>(xn, wb, xz);
  conv_kernel<<<(2 * ROWS * 64) / 256, 256, 0, stream>>>(
      xz, f_conv_w, f_conv_b, b_conv_w, b_conv_b, xc, flag);
  xproj_kernel<<<dim3(64, 9), 256, 0, stream>>>(xc, wb, dbl);
  dtproj_kernel<<<(2 * ROWS * DI) / 256, 256, 0, stream>>>(
      dbl, wb, f_dt_b, b_dt_b, dt, flag);
  scan_pass1<<<dim3(512, 3), 256, 0, stream>>>(
      dt, xc, dbl, f_A_log, b_A_log, Pch, Bch, flag);
  scan_pass2<<<dim3(512, 4), 256, 0, stream>>>(
      dt, xc, xz, dbl, f_A_log, f_Dp, b_A_log, b_Dp, Pch, Bch, y, flag);
  outproj_kernel<<<ROWS / 16, 256, 0, stream>>>(y, wb, xssm);
  ln2_kernel<<<ROWS, 256, 0, stream>>>(xssm, ln2_g, ln2_b, x2, flag);
  final_kernel<<<ROWS / 16, 256, 0, stream>>>(x2, wb, b2, d_out, flag);
}